// Round 3
// baseline (57.969 us; speedup 1.0000x reference)
//
#include <hip/hip_runtime.h>

// out[b,t,i,j] = x[b,t,i] * coeffs[(i+j) % 128],
//   x[b,t,i] = inputs[b,t,i] for i < 127, x[b,t,127] = 1.0
// inputs: [B*T, 127] f32, coeffs: [128] f32, out: [B*T, 128, 128] f32.
// One block per (b,t) row: 64 KiB output tile, coalesced nontemporal
// float4 stores (streaming writes, no L2 allocate).

typedef float float4v __attribute__((ext_vector_type(4)));

__global__ __launch_bounds__(256) void vinput_kernel(
    const float* __restrict__ in,      // [rows, 127]
    const float* __restrict__ coeffs,  // [128]
    float* __restrict__ out,           // [rows, 128, 128]
    int rows)
{
    __shared__ float xs[128];   // x row (127 inputs + 1.0 bias)
    __shared__ float cs[256];   // coeffs duplicated: cs[k] = coeffs[k % 128]

    const int tid = threadIdx.x;
    const int row = blockIdx.x;
    if (row >= rows) return;

    // Cooperative stage: threads 0..127 load coeffs (duplicated),
    // threads 128..255 load the x row (last element = 1.0 bias).
    if (tid < 128) {
        float c = coeffs[tid];
        cs[tid] = c;
        cs[tid + 128] = c;
    } else {
        int i = tid - 128;
        xs[i] = (i < 127) ? in[(size_t)row * 127 + i] : 1.0f;
    }
    __syncthreads();

    float* outp = out + (size_t)row * 16384;  // 128*128 tile

    // 16384 floats / (256 threads * 4/thread) = 16 iterations.
    // idx consecutive across tid -> perfectly coalesced 16B/lane stores.
#pragma unroll
    for (int it = 0; it < 16; ++it) {
        int idx = (it * 256 + tid) * 4;   // flat index in tile
        int i = idx >> 7;                 // row within tile
        int j = idx & 127;                // col within tile (multiple of 4)
        float xv = xs[i];
        float4v v;
        v.x = xv * cs[i + j + 0];
        v.y = xv * cs[i + j + 1];
        v.z = xv * cs[i + j + 2];
        v.w = xv * cs[i + j + 3];
        __builtin_nontemporal_store(v, reinterpret_cast<float4v*>(outp + idx));
    }
}

extern "C" void kernel_launch(void* const* d_in, const int* in_sizes, int n_in,
                              void* d_out, int out_size, void* d_ws, size_t ws_size,
                              hipStream_t stream) {
    const float* in     = (const float*)d_in[0];
    const float* coeffs = (const float*)d_in[1];
    float* out          = (float*)d_out;

    const int D = 127;                 // inputs last dim
    const int rows = in_sizes[0] / D;  // B*T = 4096

    vinput_kernel<<<rows, 256, 0, stream>>>(in, coeffs, out, rows);
}

// Round 4
// 45.299 us; speedup vs baseline: 1.2797x; 1.2797x over previous
//
#include <hip/hip_runtime.h>

// out[b,t,i,j] = x[b,t,i] * coeffs[(i+j) % 128],
//   x[b,t,i] = inputs[b,t,i] for i < 127, x[b,t,127] = 1.0
// inputs: [B*T, 127] f32, coeffs: [128] f32, out: [B*T, 128, 128] f32.
// 2048 blocks, each handles 2 rows (row and row+2048): one barrier per
// block, all blocks co-resident, coalesced plain float4 stores.

typedef float float4v __attribute__((ext_vector_type(4)));

__global__ __launch_bounds__(256) void vinput_kernel(
    const float* __restrict__ in,      // [rows, 127]
    const float* __restrict__ coeffs,  // [128]
    float* __restrict__ out,           // [rows, 128, 128]
    int half)                           // rows/2
{
    __shared__ float xs[2][128];  // two x rows (127 inputs + 1.0 bias each)
    __shared__ float cs[256];     // coeffs duplicated: cs[k] = coeffs[k%128]

    const int tid = threadIdx.x;
    const int r0 = blockIdx.x;        // first row
    const int r1 = blockIdx.x + half; // second row

    // Stage: every thread loads one xs element (2 rows x 128); threads
    // 0..127 additionally stage duplicated coeffs.
    {
        int which = tid >> 7;          // 0 or 1
        int i = tid & 127;
        int row = which ? r1 : r0;
        xs[which][i] = (i < 127) ? in[(size_t)row * 127 + i] : 1.0f;
        if (tid < 128) {
            float c = coeffs[tid];
            cs[tid] = c;
            cs[tid + 128] = c;
        }
    }
    __syncthreads();

    // Per-thread constants: j fixed, i = it*8 + (tid>>5).
    const int j  = (tid * 4) & 127;     // col within tile (multiple of 4)
    const int i0 = tid >> 5;            // row offset within tile

#pragma unroll
    for (int half_idx = 0; half_idx < 2; ++half_idx) {
        const float* xrow = xs[half_idx];
        float* outp = out + (size_t)(half_idx ? r1 : r0) * 16384;
#pragma unroll
        for (int it = 0; it < 16; ++it) {
            int i = it * 8 + i0;
            float xv = xrow[i];
            float4v v;
            v.x = xv * cs[i + j + 0];
            v.y = xv * cs[i + j + 1];
            v.z = xv * cs[i + j + 2];
            v.w = xv * cs[i + j + 3];
            *reinterpret_cast<float4v*>(outp + (i * 128 + j)) = v;
        }
    }
}

extern "C" void kernel_launch(void* const* d_in, const int* in_sizes, int n_in,
                              void* d_out, int out_size, void* d_ws, size_t ws_size,
                              hipStream_t stream) {
    const float* in     = (const float*)d_in[0];
    const float* coeffs = (const float*)d_in[1];
    float* out          = (float*)d_out;

    const int D = 127;                 // inputs last dim
    const int rows = in_sizes[0] / D;  // B*T = 4096
    const int half = rows / 2;         // 2048 blocks, 2 rows each

    vinput_kernel<<<half, 256, 0, stream>>>(in, coeffs, out, half);
}